// Round 14
// baseline (117.783 us; speedup 1.0000x reference)
//
#include <hip/hip_runtime.h>
#include <math.h>

#define B_ 2
#define S_ 2048
#define DM 1024
#define NH 16
#define HD 64

typedef unsigned short u16;
typedef unsigned int u32;
typedef __attribute__((ext_vector_type(8))) short bf16x8;
typedef __attribute__((ext_vector_type(4))) float f32x4;

// (1/sqrt(model_dim)) * log2(e): folded into Q at GEMM0 epilogue
#define C2SCALE 0.0450842200277800f

__device__ __forceinline__ u16 f2bf(float x) {
  unsigned u = __float_as_uint(x);
  u = (u + 0x7FFFu + ((u >> 16) & 1u)) >> 16;
  return (u16)u;
}

__device__ __forceinline__ u32 cvtpk(float lo, float hi) {
  u32 r;
  asm("v_cvt_pk_bf16_f32 %0, %1, %2" : "=v"(r) : "v"(lo), "v"(hi));
  return r;
}

__device__ __forceinline__ float exp2a(float x) {
  float r;
  asm("v_exp_f32 %0, %1" : "=v"(r) : "v"(x));
  return r;
}

__device__ __forceinline__ void gload_lds16(const u16* g, u16* l) {
  __builtin_amdgcn_global_load_lds((const __attribute__((address_space(1))) void*)g,
                                   (__attribute__((address_space(3))) void*)l, 16, 0, 0);
}

// sigma position within a 64-chunk (same permutation as the V^T producer)
__device__ __forceinline__ int sigpos(int w6) {
  return ((w6 >> 5) << 5) | (((w6 >> 2) & 3) << 3) | (((w6 >> 4) & 1) << 2) | (w6 & 3);
}

// per-batch exclusive prefix scan of kv_mask -> compacted positions posb,
// totals nvb, and sigma-ordered COMPACTED mask words (0xFFFF below total).
__global__ void mask_scan(const int* __restrict__ kvm, int* __restrict__ posb,
                          int* __restrict__ nvb, u16* __restrict__ mwg) {
  const int b = blockIdx.x;
  const int tid = threadIdx.x;  // 256
  const int lane = tid & 63, wv = tid >> 6;
  __shared__ int wsum[4];
  int v[8], s = 0;
  const int base = b * S_ + tid * 8;
#pragma unroll
  for (int j = 0; j < 8; j++) { v[j] = kvm[base + j] ? 1 : 0; s += v[j]; }
  int sc = s;
#pragma unroll
  for (int off = 1; off < 64; off <<= 1) {
    int t = __shfl_up(sc, off, 64);
    if (lane >= off) sc += t;
  }
  if (lane == 63) wsum[wv] = sc;
  __syncthreads();
  int woff = 0;
#pragma unroll
  for (int w = 0; w < 4; w++) woff += (w < wv) ? wsum[w] : 0;
  int run = woff + sc - s;  // exclusive prefix for this thread's chunk
#pragma unroll
  for (int j = 0; j < 8; j++) { posb[base + j] = run; run += v[j]; }
  const int total = wsum[0] + wsum[1] + wsum[2] + wsum[3];
  if (tid == 0) nvb[b] = total;
  for (int i = tid; i < S_; i += 256)
    mwg[b * S_ + (i & ~63) + sigpos(i & 63)] = (i < total) ? 0xFFFFu : 0u;
}

// fused f32->bf16 converts + V^T pad-column zeroing (PV inf/NaN safety)
__global__ void cvt_all(const float* __restrict__ q, const float* __restrict__ Wq,
                        const float* __restrict__ Wk, const float* __restrict__ Wv,
                        const float* __restrict__ Wo, const int* __restrict__ nvb,
                        u16* __restrict__ Xbf, u16* __restrict__ Wcat,
                        u16* __restrict__ Wobf, u16* __restrict__ vtbuf) {
  const int NQ4 = (B_ * S_ * DM) / 4;
  const int NW4 = (DM * DM) / 4;
  const int total = NQ4 + 4 * NW4;
  int i = blockIdx.x * blockDim.x + threadIdx.x;
  int stride = gridDim.x * blockDim.x;
  // zero V^T pad columns [nv, ceil64(nv)) for every (bh, d)
  for (int idx = i; idx < B_ * NH * HD * 64; idx += stride) {
    int col = idx & 63;
    int dd = (idx >> 6) & 63;
    int bh = idx >> 12;
    int nv = nvb[bh >> 4];
    int padw = ((nv + 63) & ~63) - nv;
    if (col < padw)
      vtbuf[((size_t)bh * HD + dd) * S_ + nv + col] = 0;
  }
  for (; i < total; i += stride) {
    const float* src;
    u16* dst;
    if (i < NQ4) {
      src = q + (size_t)i * 4; dst = Xbf + (size_t)i * 4;
    } else {
      int t = i - NQ4;
      if (t < NW4)            { src = Wq + (size_t)t * 4; dst = Wcat + (size_t)t * 4; }
      else if (t < 2 * NW4)   { src = Wk + (size_t)(t - NW4) * 4;     dst = Wcat + DM * DM + (size_t)(t - NW4) * 4; }
      else if (t < 3 * NW4)   { src = Wv + (size_t)(t - 2 * NW4) * 4; dst = Wcat + 2 * DM * DM + (size_t)(t - 2 * NW4) * 4; }
      else                    { src = Wo + (size_t)(t - 3 * NW4) * 4; dst = Wobf + (size_t)(t - 3 * NW4) * 4; }
    }
    float4 v = *(const float4*)src;
    ushort4 o;
    o.x = f2bf(v.x); o.y = f2bf(v.y); o.z = f2bf(v.z); o.w = f2bf(v.w);
    *(ushort4*)dst = o;
  }
}

// GEMM0: C[4096,3072] = X @ Wcat^T. 128x64 tile (gemm_n64 structure: 1536
// blocks = 6/CU, 12 KB LDS, 4 waves each 64x32), BK=32, XCD-swizzled.
// Q pre-scaled by C2SCALE; K/V scattered to COMPACTED kv positions (posb);
// V transposed + sigma-permuted. Invalid rows dropped.
__global__ __launch_bounds__(256, 4) void gemm_bt(
    const u16* __restrict__ A, const u16* __restrict__ Bw,
    u16* __restrict__ qo, u16* __restrict__ ko, u16* __restrict__ vo,
    const int* __restrict__ kvm, const int* __restrict__ posb) {
  __shared__ __align__(16) u16 As[128 * 32];
  __shared__ __align__(16) u16 Bs[64 * 32];
  const int K = DM;
  const int tid = threadIdx.x;
  const int wv = tid >> 6, lane = tid & 63;
  const int g = lane >> 4, c = lane & 15;
  const int wr = wv >> 1, wc = wv & 1;
  const int L = blockIdx.y * gridDim.x + blockIdx.x;
  const int cpx = (gridDim.x * gridDim.y) >> 3;
  const int Ls = (L & 7) * cpx + (L >> 3);
  const int Mb = (Ls & 31) << 7, Nb = (Ls >> 5) << 6;

  f32x4 acc[4][2];
#pragma unroll
  for (int i = 0; i < 4; i++)
#pragma unroll
    for (int j = 0; j < 2; j++) acc[i][j] = f32x4{0.f, 0.f, 0.f, 0.f};

  for (int kb = 0; kb < K; kb += 32) {
#pragma unroll
    for (int it = 0; it < 2; ++it) {
      int id = it * 256 + tid;
      int m = id >> 2, kk = (id & 3) * 8;
      gload_lds16(A + (size_t)(Mb + m) * K + kb + kk, As + (it * 4 + wv) * 512);
    }
    {
      int m = tid >> 2, kk = (tid & 3) * 8;
      gload_lds16(Bw + (size_t)(Nb + m) * K + kb + kk, Bs + wv * 512);
    }
    __syncthreads();
    bf16x8 af[4], bfr[2];
#pragma unroll
    for (int mi = 0; mi < 4; mi++)
      af[mi] = *(const bf16x8*)(As + (wr * 64 + mi * 16 + c) * 32 + g * 8);
#pragma unroll
    for (int ni = 0; ni < 2; ni++)
      bfr[ni] = *(const bf16x8*)(Bs + (wc * 32 + ni * 16 + c) * 32 + g * 8);
#pragma unroll
    for (int mi = 0; mi < 4; mi++)
#pragma unroll
      for (int ni = 0; ni < 2; ni++)
        acc[mi][ni] = __builtin_amdgcn_mfma_f32_16x16x32_bf16(af[mi], bfr[ni], acc[mi][ni], 0, 0, 0);
    __syncthreads();
  }

  const int nbase = Nb + wc * 32 + c;
  const int which = nbase >> 10;  // block-uniform (Nb 64-aligned, span < 64)
  if (which == 0) {
#pragma unroll
    for (int mi = 0; mi < 4; mi++) {
#pragma unroll
      for (int ni = 0; ni < 2; ni++) {
        int nn = nbase + ni * 16;
        int h = nn >> 6, d = nn & 63;
#pragma unroll
        for (int r = 0; r < 4; r++) {
          int row = Mb + wr * 64 + mi * 16 + g * 4 + r;
          int b0 = row >> 11, s0 = row & 2047;
          qo[(((size_t)(b0 * NH + h)) * S_ + s0) * HD + d] =
              f2bf(acc[mi][ni][r] * C2SCALE);
        }
      }
    }
  } else if (which == 1) {
#pragma unroll
    for (int mi = 0; mi < 4; mi++) {
#pragma unroll
      for (int r = 0; r < 4; r++) {
        int row = Mb + wr * 64 + mi * 16 + g * 4 + r;
        int b0 = row >> 11, s0 = row & 2047;
        if (kvm[b0 * S_ + s0]) {
          int p = posb[b0 * S_ + s0];
#pragma unroll
          for (int ni = 0; ni < 2; ni++) {
            int nn = (nbase + ni * 16) & 1023;
            ko[((size_t)(b0 * NH + (nn >> 6)) * S_ + p) * HD + (nn & 63)] =
                f2bf(acc[mi][ni][r]);
          }
        }
      }
    }
  } else {
#pragma unroll
    for (int mi = 0; mi < 4; mi++) {
#pragma unroll
      for (int r = 0; r < 4; r++) {
        int row = Mb + wr * 64 + mi * 16 + g * 4 + r;
        int b0 = row >> 11, s0 = row & 2047;
        if (kvm[b0 * S_ + s0]) {
          int p = posb[b0 * S_ + s0];
          int dst = (p & ~63) + sigpos(p & 63);
#pragma unroll
          for (int ni = 0; ni < 2; ni++) {
            int nn = (nbase + ni * 16) & 1023;
            vo[((size_t)((b0 * NH + (nn >> 6)) * HD + (nn & 63))) * S_ + dst] =
                f2bf(acc[mi][ni][r]);
          }
        }
      }
    }
  }
}

// GEMM1: out[4096,1024] = A @ Wo^T + bo. 128x64 tile -> 512 blocks (4/CU).
__global__ __launch_bounds__(256, 4) void gemm_n64(
    const u16* __restrict__ A, const u16* __restrict__ Bw,
    const float* __restrict__ bias, float* __restrict__ fo) {
  __shared__ __align__(16) u16 As[128 * 32];
  __shared__ __align__(16) u16 Bs[64 * 32];
  const int K = DM, N = DM;
  const int tid = threadIdx.x;
  const int wv = tid >> 6, lane = tid & 63;
  const int g = lane >> 4, c = lane & 15;
  const int wr = wv >> 1, wc = wv & 1;
  const int L = blockIdx.x;
  const int Ls = (L & 7) * 64 + (L >> 3);
  const int Mb = (Ls & 31) << 7, Nb = (Ls >> 5) << 6;

  f32x4 acc[4][2];
#pragma unroll
  for (int i = 0; i < 4; i++)
#pragma unroll
    for (int j = 0; j < 2; j++) acc[i][j] = f32x4{0.f, 0.f, 0.f, 0.f};

  for (int kb = 0; kb < K; kb += 32) {
#pragma unroll
    for (int it = 0; it < 2; ++it) {
      int id = it * 256 + tid;
      int m = id >> 2, kk = (id & 3) * 8;
      gload_lds16(A + (size_t)(Mb + m) * K + kb + kk, As + (it * 4 + wv) * 512);
    }
    {
      int m = tid >> 2, kk = (tid & 3) * 8;
      gload_lds16(Bw + (size_t)(Nb + m) * K + kb + kk, Bs + wv * 512);
    }
    __syncthreads();
    bf16x8 af[4], bfr[2];
#pragma unroll
    for (int mi = 0; mi < 4; mi++)
      af[mi] = *(const bf16x8*)(As + (wr * 64 + mi * 16 + c) * 32 + g * 8);
#pragma unroll
    for (int ni = 0; ni < 2; ni++)
      bfr[ni] = *(const bf16x8*)(Bs + (wc * 32 + ni * 16 + c) * 32 + g * 8);
#pragma unroll
    for (int mi = 0; mi < 4; mi++)
#pragma unroll
      for (int ni = 0; ni < 2; ni++)
        acc[mi][ni] = __builtin_amdgcn_mfma_f32_16x16x32_bf16(af[mi], bfr[ni], acc[mi][ni], 0, 0, 0);
    __syncthreads();
  }

#pragma unroll
  for (int mi = 0; mi < 4; mi++) {
#pragma unroll
    for (int ni = 0; ni < 2; ni++) {
      int n = Nb + wc * 32 + ni * 16 + c;
      float bv = bias[n];
#pragma unroll
      for (int r = 0; r < 4; r++) {
        int row = Mb + wr * 64 + mi * 16 + g * 4 + r;
        fo[(size_t)row * N + n] = acc[mi][ni][r] + bv;
      }
    }
  }
}

// Flash attention over COMPACTED kv (length nvb[b], tiles NT=ceil/64).
// Swapped-operand, fixed-shift softmax, KVBLK=64, 8 waves x 16 q.
// Reg-staged double-buffered K/V LDS, XOR-swizzled (conflict-free b128).
// p = v_exp(s); tail masking via AND on packed P; l via persistent MFMA acc.
__global__ __launch_bounds__(512, 4) void attn_kernel(
    const u16* __restrict__ qb, const u16* __restrict__ kb,
    const u16* __restrict__ vtb, const u16* __restrict__ mwg,
    const int* __restrict__ nvb, u16* __restrict__ ob) {
  __shared__ __align__(16) u16 Kl[2][64 * 64];
  __shared__ __align__(16) u16 Vl[2][64 * 64];
  __shared__ __align__(16) u16 MW[S_];

  const int tid = threadIdx.x;
  const int wv = tid >> 6, lane = tid & 63;
  const int g = lane >> 4, c = lane & 15;

  // XCD-aware bijective remap: XCD x owns bh range [4x,4x+4).
  const int L = blockIdx.x;
  const int j = L >> 3;
  const int bh = ((L & 7) << 2) | (j >> 4);
  const int qi = j & 15;
  const int b = bh >> 4, h = bh & 15;
  const int q0 = qi * 128;
  const size_t bhbase = (size_t)bh * (S_ * HD);
  const int NT = (nvb[b] + 63) >> 6;

  // compacted sigma-ordered mask words for this batch
  ((uint2*)MW)[tid] = ((const uint2*)(mwg + b * S_))[tid];

  bf16x8 qf[2];
#pragma unroll
  for (int ks = 0; ks < 2; ks++)
    qf[ks] = *(const bf16x8*)(qb + bhbase + (size_t)(q0 + wv * 16 + c) * HD + ks * 32 + g * 8);

  f32x4 Oa[4];
#pragma unroll
  for (int di = 0; di < 4; di++) Oa[di] = f32x4{0.f, 0.f, 0.f, 0.f};
  f32x4 lacc = f32x4{0.f, 0.f, 0.f, 0.f};

  union { u32 u[4]; bf16x8 v; } ones;
#pragma unroll
  for (int w = 0; w < 4; w++) ones.u[w] = 0x3F803F80u;

  const int srow = tid >> 3;
  const int scol8 = tid & 7;
  const u16* kg = kb + bhbase + (size_t)srow * HD + scol8 * 8;    // +t*4096
  const u16* vg = vtb + bhbase + (size_t)srow * S_ + scol8 * 8;   // +t*64
  const int wslot = scol8 ^ (srow & 7);
  u16* kld = &Kl[0][srow * 64 + wslot * 8];
  u16* vld = &Vl[0][srow * 64 + wslot * 8];

  // prologue: tile 0 -> regs -> buf0; tile 1 -> regs (NT >= 1 always)
  bf16x8 krg = *(const bf16x8*)kg;
  bf16x8 vrg = *(const bf16x8*)vg;
  *(bf16x8*)kld = krg;
  *(bf16x8*)vld = vrg;
  krg = *(const bf16x8*)(kg + 64 * HD);
  vrg = *(const bf16x8*)(vg + 64);
  __syncthreads();

  const int swz = c & 7;

  for (int t = 0; t < NT; ++t) {
    const int cur = t & 1;
    if (t + 1 < NT) {
      *(bf16x8*)(kld + (cur ^ 1) * 4096) = krg;
      *(bf16x8*)(vld + (cur ^ 1) * 4096) = vrg;
      if (t + 2 < NT) {
        krg = *(const bf16x8*)(kg + (t + 2) * (64 * HD));
        vrg = *(const bf16x8*)(vg + (t + 2) * 64);
      }
    }
    const u16* KB = &Kl[cur][0];
    const u16* VB = &Vl[cur][0];

    // S^T: Sa[ni], row = kv (ni*16 + 4g + r), col = q (c)
    f32x4 Sa[4];
#pragma unroll
    for (int ni = 0; ni < 4; ni++) Sa[ni] = f32x4{0.f, 0.f, 0.f, 0.f};
    __builtin_amdgcn_s_setprio(1);
#pragma unroll
    for (int ks = 0; ks < 2; ks++) {
      bf16x8 kf[4];
#pragma unroll
      for (int ni = 0; ni < 4; ni++)
        kf[ni] = *(const bf16x8*)&KB[(ni * 16 + c) * 64 + (((4 * ks + g) ^ swz) * 8)];
#pragma unroll
      for (int ni = 0; ni < 4; ni++)
        Sa[ni] = __builtin_amdgcn_mfma_f32_16x16x32_bf16(kf[ni], qf[ks], Sa[ni], 0, 0, 0);
    }
    __builtin_amdgcn_s_setprio(0);

    // p = 2^s (fixed-shift softmax); tail mask via bitwise AND
    bf16x8 Pa[2];
#pragma unroll
    for (int ks = 0; ks < 2; ks++) {
      uint4 mw = *(const uint4*)&MW[t * 64 + ks * 32 + g * 8];
      union { u32 u[4]; bf16x8 v; } pw;
      pw.u[0] = cvtpk(exp2a(Sa[2 * ks][0]), exp2a(Sa[2 * ks][1])) & mw.x;
      pw.u[1] = cvtpk(exp2a(Sa[2 * ks][2]), exp2a(Sa[2 * ks][3])) & mw.y;
      pw.u[2] = cvtpk(exp2a(Sa[2 * ks + 1][0]), exp2a(Sa[2 * ks + 1][1])) & mw.z;
      pw.u[3] = cvtpk(exp2a(Sa[2 * ks + 1][2]), exp2a(Sa[2 * ks + 1][3])) & mw.w;
      Pa[ks] = pw.v;
    }

    // l accumulates over all tiles; O^T += V^T_frag * P_frag
    __builtin_amdgcn_s_setprio(1);
    lacc = __builtin_amdgcn_mfma_f32_16x16x32_bf16(ones.v, Pa[0], lacc, 0, 0, 0);
    lacc = __builtin_amdgcn_mfma_f32_16x16x32_bf16(ones.v, Pa[1], lacc, 0, 0, 0);
#pragma unroll
    for (int ks = 0; ks < 2; ks++) {
      bf16x8 vf[4];
#pragma unroll
      for (int di = 0; di < 4; di++)
        vf[di] = *(const bf16x8*)&VB[(di * 16 + c) * 64 + (((4 * ks + g) ^ swz) * 8)];
#pragma unroll
      for (int di = 0; di < 4; di++)
        Oa[di] = __builtin_amdgcn_mfma_f32_16x16x32_bf16(vf[di], Pa[ks], Oa[di], 0, 0, 0);
    }
    __builtin_amdgcn_s_setprio(0);

    // barrier without vmcnt drain (LDS ordering only)
    asm volatile("s_waitcnt lgkmcnt(0)\n\ts_barrier" ::: "memory");
  }

  // epilogue
  float inv = 1.f / lacc[0];
  int q = q0 + wv * 16 + c;
  size_t base = ((size_t)(b * S_ + q)) * DM + (size_t)h * HD;
#pragma unroll
  for (int di = 0; di < 4; di++) {
    uint2 o;
    o.x = cvtpk(Oa[di][0] * inv, Oa[di][1] * inv);
    o.y = cvtpk(Oa[di][2] * inv, Oa[di][3] * inv);
    *(uint2*)(ob + base + di * 16 + g * 4) = o;
  }
}

extern "C" void kernel_launch(void* const* d_in, const int* in_sizes, int n_in,
                              void* d_out, int out_size, void* d_ws, size_t ws_size,
                              hipStream_t stream) {
  const float* q  = (const float*)d_in[0];
  const int* kvm  = (const int*)d_in[1];
  const float* Wq = (const float*)d_in[2];
  const float* Wk = (const float*)d_in[3];
  const float* Wv = (const float*)d_in[4];
  const float* Wo = (const float*)d_in[5];
  const float* bo = (const float*)d_in[6];
  float* out = (float*)d_out;
  char* ws = (char*)d_ws;

  u16* Xbf   = (u16*)(ws);                       // 8 MB; reused as obuf post-gemm0
  u16* Wcat  = (u16*)(ws + (8u << 20));          // 6 MB (Wq|Wk|Wv)
  u16* Wobf  = (u16*)(ws + (14u << 20));         // 2 MB
  u16* qbuf  = (u16*)(ws + (16u << 20));         // 8 MB (B,H,S,64), pre-scaled
  u16* kbuf  = (u16*)(ws + (24u << 20));         // 8 MB compacted
  u16* vtbuf = (u16*)(ws + (32u << 20));         // 8 MB (B,H,64,S) sigma, compacted
  u16* mwg   = (u16*)(ws + (40u << 20));         // 8 KB compacted mask words
  int* posb  = (int*)(ws + (41u << 20));         // 16 KB prefix positions
  int* nvb   = (int*)(ws + (42u << 20));         // 8 B totals
  u16* obuf  = Xbf;

  mask_scan<<<B_, 256, 0, stream>>>(kvm, posb, nvb, mwg);
  cvt_all<<<2048, 256, 0, stream>>>(q, Wq, Wk, Wv, Wo, nvb, Xbf, Wcat, Wobf, vtbuf);
  gemm_bt<<<dim3(32, 48), 256, 0, stream>>>(Xbf, Wcat, qbuf, kbuf, vtbuf,
                                            kvm, posb);
  attn_kernel<<<512, 512, 0, stream>>>(qbuf, kbuf, vtbuf, mwg, nvb, obuf);
  gemm_n64<<<512, 256, 0, stream>>>(obuf, Wobf, bo, out);
}

// Round 15
// 109.331 us; speedup vs baseline: 1.0773x; 1.0773x over previous
//
#include <hip/hip_runtime.h>
#include <math.h>

#define B_ 2
#define S_ 2048
#define DM 1024
#define NH 16
#define HD 64

typedef unsigned short u16;
typedef unsigned int u32;
typedef __attribute__((ext_vector_type(8))) short bf16x8;
typedef __attribute__((ext_vector_type(4))) float f32x4;

// (1/sqrt(model_dim)) * log2(e): folded into Q at GEMM0 epilogue
#define C2SCALE 0.0450842200277800f

__device__ __forceinline__ u16 f2bf(float x) {
  unsigned u = __float_as_uint(x);
  u = (u + 0x7FFFu + ((u >> 16) & 1u)) >> 16;
  return (u16)u;
}

__device__ __forceinline__ u32 cvtpk(float lo, float hi) {
  u32 r;
  asm("v_cvt_pk_bf16_f32 %0, %1, %2" : "=v"(r) : "v"(lo), "v"(hi));
  return r;
}

__device__ __forceinline__ float exp2a(float x) {
  float r;
  asm("v_exp_f32 %0, %1" : "=v"(r) : "v"(x));
  return r;
}

__device__ __forceinline__ void gload_lds16(const u16* g, u16* l) {
  __builtin_amdgcn_global_load_lds((const __attribute__((address_space(1))) void*)g,
                                   (__attribute__((address_space(3))) void*)l, 16, 0, 0);
}

// sigma position within a 64-chunk (same permutation as the V^T producer)
__device__ __forceinline__ int sigpos(int w6) {
  return ((w6 >> 5) << 5) | (((w6 >> 2) & 3) << 3) | (((w6 >> 4) & 1) << 2) | (w6 & 3);
}

// per-batch exclusive prefix scan of kv_mask -> compacted positions posb,
// totals nvb, and sigma-ordered COMPACTED mask words (0xFFFF below total).
__global__ void mask_scan(const int* __restrict__ kvm, int* __restrict__ posb,
                          int* __restrict__ nvb, u16* __restrict__ mwg) {
  const int b = blockIdx.x;
  const int tid = threadIdx.x;  // 256
  const int lane = tid & 63, wv = tid >> 6;
  __shared__ int wsum[4];
  int v[8], s = 0;
  const int base = b * S_ + tid * 8;
#pragma unroll
  for (int j = 0; j < 8; j++) { v[j] = kvm[base + j] ? 1 : 0; s += v[j]; }
  int sc = s;
#pragma unroll
  for (int off = 1; off < 64; off <<= 1) {
    int t = __shfl_up(sc, off, 64);
    if (lane >= off) sc += t;
  }
  if (lane == 63) wsum[wv] = sc;
  __syncthreads();
  int woff = 0;
#pragma unroll
  for (int w = 0; w < 4; w++) woff += (w < wv) ? wsum[w] : 0;
  int run = woff + sc - s;  // exclusive prefix for this thread's chunk
#pragma unroll
  for (int j = 0; j < 8; j++) { posb[base + j] = run; run += v[j]; }
  const int total = wsum[0] + wsum[1] + wsum[2] + wsum[3];
  if (tid == 0) nvb[b] = total;
  for (int i = tid; i < S_; i += 256)
    mwg[b * S_ + (i & ~63) + sigpos(i & 63)] = (i < total) ? 0xFFFFu : 0u;
}

// fused f32->bf16 converts + V^T pad-column zeroing (PV inf/NaN safety)
__global__ void cvt_all(const float* __restrict__ q, const float* __restrict__ Wq,
                        const float* __restrict__ Wk, const float* __restrict__ Wv,
                        const float* __restrict__ Wo, const int* __restrict__ nvb,
                        u16* __restrict__ Xbf, u16* __restrict__ Wcat,
                        u16* __restrict__ Wobf, u16* __restrict__ vtbuf) {
  const int NQ4 = (B_ * S_ * DM) / 4;
  const int NW4 = (DM * DM) / 4;
  const int total = NQ4 + 4 * NW4;
  int i = blockIdx.x * blockDim.x + threadIdx.x;
  int stride = gridDim.x * blockDim.x;
  // zero V^T pad columns [nv, ceil64(nv)) for every (bh, d)
  for (int idx = i; idx < B_ * NH * HD * 64; idx += stride) {
    int col = idx & 63;
    int dd = (idx >> 6) & 63;
    int bh = idx >> 12;
    int nv = nvb[bh >> 4];
    int padw = ((nv + 63) & ~63) - nv;
    if (col < padw)
      vtbuf[((size_t)bh * HD + dd) * S_ + nv + col] = 0;
  }
  for (; i < total; i += stride) {
    const float* src;
    u16* dst;
    if (i < NQ4) {
      src = q + (size_t)i * 4; dst = Xbf + (size_t)i * 4;
    } else {
      int t = i - NQ4;
      if (t < NW4)            { src = Wq + (size_t)t * 4; dst = Wcat + (size_t)t * 4; }
      else if (t < 2 * NW4)   { src = Wk + (size_t)(t - NW4) * 4;     dst = Wcat + DM * DM + (size_t)(t - NW4) * 4; }
      else if (t < 3 * NW4)   { src = Wv + (size_t)(t - 2 * NW4) * 4; dst = Wcat + 2 * DM * DM + (size_t)(t - 2 * NW4) * 4; }
      else                    { src = Wo + (size_t)(t - 3 * NW4) * 4; dst = Wobf + (size_t)(t - 3 * NW4) * 4; }
    }
    float4 v = *(const float4*)src;
    ushort4 o;
    o.x = f2bf(v.x); o.y = f2bf(v.y); o.z = f2bf(v.z); o.w = f2bf(v.w);
    *(ushort4*)dst = o;
  }
}

// GEMM0: C[4096,3072] = X @ Wcat^T. 128x128 tile, BK=32, 768 blocks (3/CU),
// XCD-swizzled. Staging = attn-style reg-staged DOUBLE-BUFFERED LDS with
// XOR-swizzle (fused-pair layout: (m,k) -> row'=m>>1, col=(m&1)*32+k,
// slot = chunk ^ (row'&7)); in-loop barrier is lgkmcnt-only (no vmcnt drain)
// so t+2 prefetch loads stay in flight across ~2 compute phases.
// Q pre-scaled by C2SCALE; K/V scattered to COMPACTED kv positions (posb);
// V transposed + sigma-permuted. Invalid rows dropped.
__global__ __launch_bounds__(256, 3) void gemm_bt(
    const u16* __restrict__ A, const u16* __restrict__ Bw,
    u16* __restrict__ qo, u16* __restrict__ ko, u16* __restrict__ vo,
    const int* __restrict__ kvm, const int* __restrict__ posb) {
  __shared__ __align__(16) u16 As[2][64 * 64];
  __shared__ __align__(16) u16 Bs[2][64 * 64];
  const int K = DM;
  const int tid = threadIdx.x;
  const int wv = tid >> 6, lane = tid & 63;
  const int g = lane >> 4, c = lane & 15;
  const int wr = wv >> 1, wc = wv & 1;
  const int L = blockIdx.y * gridDim.x + blockIdx.x;
  const int cpx = (gridDim.x * gridDim.y) >> 3;
  const int Ls = (L & 7) * cpx + (L >> 3);
  const int Mb = (Ls & 31) << 7, Nb = (Ls >> 5) << 7;

  f32x4 acc[4][4];
#pragma unroll
  for (int i = 0; i < 4; i++)
#pragma unroll
    for (int j = 0; j < 4; j++) acc[i][j] = f32x4{0.f, 0.f, 0.f, 0.f};

  // staging: thread owns chunks (srow, scol8) and (srow+32, scol8);
  // logical m = row'*2 + (scol8>>2), k-chunk = scol8&3.
  const int srow = tid >> 3;      // 0..31
  const int scol8 = tid & 7;
  const int m1 = srow * 2 + (scol8 >> 2);
  const int kkc = (scol8 & 3) * 8;
  const u16* ag1 = A + (size_t)(Mb + m1) * K + kkc;      // + t*32
  const u16* ag2 = ag1 + (size_t)64 * K;
  const u16* bg1 = Bw + (size_t)(Nb + m1) * K + kkc;
  const u16* bg2 = bg1 + (size_t)64 * K;
  const int slot = scol8 ^ (srow & 7);                   // (srow+32)&7 == srow&7
  u16* al1 = &As[0][srow * 64 + slot * 8];
  u16* al2 = &As[0][(srow + 32) * 64 + slot * 8];
  u16* bl1 = &Bs[0][srow * 64 + slot * 8];
  u16* bl2 = &Bs[0][(srow + 32) * 64 + slot * 8];

  // prologue: tile0 -> regs -> buf0; tile1 -> regs
  bf16x8 ar0 = *(const bf16x8*)ag1, ar1 = *(const bf16x8*)ag2;
  bf16x8 br0 = *(const bf16x8*)bg1, br1 = *(const bf16x8*)bg2;
  *(bf16x8*)al1 = ar0; *(bf16x8*)al2 = ar1;
  *(bf16x8*)bl1 = br0; *(bf16x8*)bl2 = br1;
  ar0 = *(const bf16x8*)(ag1 + 32); ar1 = *(const bf16x8*)(ag2 + 32);
  br0 = *(const bf16x8*)(bg1 + 32); br1 = *(const bf16x8*)(bg2 + 32);
  __syncthreads();

  // lane-constant fragment read offsets (swizzle inverts to logical k = g*8)
  const int off = ((((c & 1) << 2) | g) ^ (c >> 1)) << 3;
  const int arb = (wr * 32 + (c >> 1)) * 64 + off;
  const int brb = (wc * 32 + (c >> 1)) * 64 + off;

  for (int t = 0; t < 32; ++t) {
    const int cur = t & 1;
    if (t + 1 < 32) {
      const int nb = (cur ^ 1) * 4096;
      *(bf16x8*)(al1 + nb) = ar0; *(bf16x8*)(al2 + nb) = ar1;
      *(bf16x8*)(bl1 + nb) = br0; *(bf16x8*)(bl2 + nb) = br1;
      if (t + 2 < 32) {
        ar0 = *(const bf16x8*)(ag1 + (t + 2) * 32);
        ar1 = *(const bf16x8*)(ag2 + (t + 2) * 32);
        br0 = *(const bf16x8*)(bg1 + (t + 2) * 32);
        br1 = *(const bf16x8*)(bg2 + (t + 2) * 32);
      }
    }
    const u16* AB = &As[cur][0];
    const u16* BB = &Bs[cur][0];
    bf16x8 af[4], bfr[4];
#pragma unroll
    for (int mi = 0; mi < 4; mi++)
      af[mi] = *(const bf16x8*)&AB[arb + mi * 512];
#pragma unroll
    for (int ni = 0; ni < 4; ni++)
      bfr[ni] = *(const bf16x8*)&BB[brb + ni * 512];
#pragma unroll
    for (int mi = 0; mi < 4; mi++)
#pragma unroll
      for (int ni = 0; ni < 4; ni++)
        acc[mi][ni] = __builtin_amdgcn_mfma_f32_16x16x32_bf16(af[mi], bfr[ni], acc[mi][ni], 0, 0, 0);
    asm volatile("s_waitcnt lgkmcnt(0)\n\ts_barrier" ::: "memory");
  }

  const int nbase = Nb + wc * 64 + c;
  const int which = nbase >> 10;  // block-uniform (Nb is 128-aligned)
  if (which == 0) {
#pragma unroll
    for (int mi = 0; mi < 4; mi++) {
#pragma unroll
      for (int ni = 0; ni < 4; ni++) {
        int nn = nbase + ni * 16;
        int h = nn >> 6, d = nn & 63;
#pragma unroll
        for (int r = 0; r < 4; r++) {
          int row = Mb + wr * 64 + mi * 16 + g * 4 + r;
          int b0 = row >> 11, s0 = row & 2047;
          qo[(((size_t)(b0 * NH + h)) * S_ + s0) * HD + d] =
              f2bf(acc[mi][ni][r] * C2SCALE);
        }
      }
    }
  } else if (which == 1) {
#pragma unroll
    for (int mi = 0; mi < 4; mi++) {
#pragma unroll
      for (int r = 0; r < 4; r++) {
        int row = Mb + wr * 64 + mi * 16 + g * 4 + r;
        int b0 = row >> 11, s0 = row & 2047;
        if (kvm[b0 * S_ + s0]) {
          int p = posb[b0 * S_ + s0];
#pragma unroll
          for (int ni = 0; ni < 4; ni++) {
            int nn = (nbase + ni * 16) & 1023;
            ko[((size_t)(b0 * NH + (nn >> 6)) * S_ + p) * HD + (nn & 63)] =
                f2bf(acc[mi][ni][r]);
          }
        }
      }
    }
  } else {
#pragma unroll
    for (int mi = 0; mi < 4; mi++) {
#pragma unroll
      for (int r = 0; r < 4; r++) {
        int row = Mb + wr * 64 + mi * 16 + g * 4 + r;
        int b0 = row >> 11, s0 = row & 2047;
        if (kvm[b0 * S_ + s0]) {
          int p = posb[b0 * S_ + s0];
          int dst = (p & ~63) + sigpos(p & 63);
#pragma unroll
          for (int ni = 0; ni < 4; ni++) {
            int nn = (nbase + ni * 16) & 1023;
            vo[((size_t)((b0 * NH + (nn >> 6)) * HD + (nn & 63))) * S_ + dst] =
                f2bf(acc[mi][ni][r]);
          }
        }
      }
    }
  }
}

// GEMM1: out[4096,1024] = A @ Wo^T + bo. 128x64 tile -> 512 blocks (4/CU).
__global__ __launch_bounds__(256, 4) void gemm_n64(
    const u16* __restrict__ A, const u16* __restrict__ Bw,
    const float* __restrict__ bias, float* __restrict__ fo) {
  __shared__ __align__(16) u16 As[128 * 32];
  __shared__ __align__(16) u16 Bs[64 * 32];
  const int K = DM, N = DM;
  const int tid = threadIdx.x;
  const int wv = tid >> 6, lane = tid & 63;
  const int g = lane >> 4, c = lane & 15;
  const int wr = wv >> 1, wc = wv & 1;
  const int L = blockIdx.x;
  const int Ls = (L & 7) * 64 + (L >> 3);
  const int Mb = (Ls & 31) << 7, Nb = (Ls >> 5) << 6;

  f32x4 acc[4][2];
#pragma unroll
  for (int i = 0; i < 4; i++)
#pragma unroll
    for (int j = 0; j < 2; j++) acc[i][j] = f32x4{0.f, 0.f, 0.f, 0.f};

  for (int kb = 0; kb < K; kb += 32) {
#pragma unroll
    for (int it = 0; it < 2; ++it) {
      int id = it * 256 + tid;
      int m = id >> 2, kk = (id & 3) * 8;
      gload_lds16(A + (size_t)(Mb + m) * K + kb + kk, As + (it * 4 + wv) * 512);
    }
    {
      int m = tid >> 2, kk = (tid & 3) * 8;
      gload_lds16(Bw + (size_t)(Nb + m) * K + kb + kk, Bs + wv * 512);
    }
    __syncthreads();
    bf16x8 af[4], bfr[2];
#pragma unroll
    for (int mi = 0; mi < 4; mi++)
      af[mi] = *(const bf16x8*)(As + (wr * 64 + mi * 16 + c) * 32 + g * 8);
#pragma unroll
    for (int ni = 0; ni < 2; ni++)
      bfr[ni] = *(const bf16x8*)(Bs + (wc * 32 + ni * 16 + c) * 32 + g * 8);
#pragma unroll
    for (int mi = 0; mi < 4; mi++)
#pragma unroll
      for (int ni = 0; ni < 2; ni++)
        acc[mi][ni] = __builtin_amdgcn_mfma_f32_16x16x32_bf16(af[mi], bfr[ni], acc[mi][ni], 0, 0, 0);
    __syncthreads();
  }

#pragma unroll
  for (int mi = 0; mi < 4; mi++) {
#pragma unroll
    for (int ni = 0; ni < 2; ni++) {
      int n = Nb + wc * 32 + ni * 16 + c;
      float bv = bias[n];
#pragma unroll
      for (int r = 0; r < 4; r++) {
        int row = Mb + wr * 64 + mi * 16 + g * 4 + r;
        fo[(size_t)row * N + n] = acc[mi][ni][r] + bv;
      }
    }
  }
}

// Flash attention over COMPACTED kv (length nvb[b], tiles NT=ceil/64).
// Swapped-operand, fixed-shift softmax, KVBLK=64, 8 waves x 16 q.
// Reg-staged double-buffered K/V LDS, XOR-swizzled (conflict-free b128).
// p = v_exp(s); tail masking via AND on packed P; l via persistent MFMA acc.
__global__ __launch_bounds__(512, 4) void attn_kernel(
    const u16* __restrict__ qb, const u16* __restrict__ kb,
    const u16* __restrict__ vtb, const u16* __restrict__ mwg,
    const int* __restrict__ nvb, u16* __restrict__ ob) {
  __shared__ __align__(16) u16 Kl[2][64 * 64];
  __shared__ __align__(16) u16 Vl[2][64 * 64];
  __shared__ __align__(16) u16 MW[S_];

  const int tid = threadIdx.x;
  const int wv = tid >> 6, lane = tid & 63;
  const int g = lane >> 4, c = lane & 15;

  // XCD-aware bijective remap: XCD x owns bh range [4x,4x+4).
  const int L = blockIdx.x;
  const int j = L >> 3;
  const int bh = ((L & 7) << 2) | (j >> 4);
  const int qi = j & 15;
  const int b = bh >> 4, h = bh & 15;
  const int q0 = qi * 128;
  const size_t bhbase = (size_t)bh * (S_ * HD);
  const int NT = (nvb[b] + 63) >> 6;

  // compacted sigma-ordered mask words for this batch
  ((uint2*)MW)[tid] = ((const uint2*)(mwg + b * S_))[tid];

  bf16x8 qf[2];
#pragma unroll
  for (int ks = 0; ks < 2; ks++)
    qf[ks] = *(const bf16x8*)(qb + bhbase + (size_t)(q0 + wv * 16 + c) * HD + ks * 32 + g * 8);

  f32x4 Oa[4];
#pragma unroll
  for (int di = 0; di < 4; di++) Oa[di] = f32x4{0.f, 0.f, 0.f, 0.f};
  f32x4 lacc = f32x4{0.f, 0.f, 0.f, 0.f};

  union { u32 u[4]; bf16x8 v; } ones;
#pragma unroll
  for (int w = 0; w < 4; w++) ones.u[w] = 0x3F803F80u;

  const int srow = tid >> 3;
  const int scol8 = tid & 7;
  const u16* kg = kb + bhbase + (size_t)srow * HD + scol8 * 8;    // +t*4096
  const u16* vg = vtb + bhbase + (size_t)srow * S_ + scol8 * 8;   // +t*64
  const int wslot = scol8 ^ (srow & 7);
  u16* kld = &Kl[0][srow * 64 + wslot * 8];
  u16* vld = &Vl[0][srow * 64 + wslot * 8];

  // prologue: tile 0 -> regs -> buf0; tile 1 -> regs (NT >= 1 always)
  bf16x8 krg = *(const bf16x8*)kg;
  bf16x8 vrg = *(const bf16x8*)vg;
  *(bf16x8*)kld = krg;
  *(bf16x8*)vld = vrg;
  krg = *(const bf16x8*)(kg + 64 * HD);
  vrg = *(const bf16x8*)(vg + 64);
  __syncthreads();

  const int swz = c & 7;

  for (int t = 0; t < NT; ++t) {
    const int cur = t & 1;
    if (t + 1 < NT) {
      *(bf16x8*)(kld + (cur ^ 1) * 4096) = krg;
      *(bf16x8*)(vld + (cur ^ 1) * 4096) = vrg;
      if (t + 2 < NT) {
        krg = *(const bf16x8*)(kg + (t + 2) * (64 * HD));
        vrg = *(const bf16x8*)(vg + (t + 2) * 64);
      }
    }
    const u16* KB = &Kl[cur][0];
    const u16* VB = &Vl[cur][0];

    // S^T: Sa[ni], row = kv (ni*16 + 4g + r), col = q (c)
    f32x4 Sa[4];
#pragma unroll
    for (int ni = 0; ni < 4; ni++) Sa[ni] = f32x4{0.f, 0.f, 0.f, 0.f};
    __builtin_amdgcn_s_setprio(1);
#pragma unroll
    for (int ks = 0; ks < 2; ks++) {
      bf16x8 kf[4];
#pragma unroll
      for (int ni = 0; ni < 4; ni++)
        kf[ni] = *(const bf16x8*)&KB[(ni * 16 + c) * 64 + (((4 * ks + g) ^ swz) * 8)];
#pragma unroll
      for (int ni = 0; ni < 4; ni++)
        Sa[ni] = __builtin_amdgcn_mfma_f32_16x16x32_bf16(kf[ni], qf[ks], Sa[ni], 0, 0, 0);
    }
    __builtin_amdgcn_s_setprio(0);

    // p = 2^s (fixed-shift softmax); tail mask via bitwise AND
    bf16x8 Pa[2];
#pragma unroll
    for (int ks = 0; ks < 2; ks++) {
      uint4 mw = *(const uint4*)&MW[t * 64 + ks * 32 + g * 8];
      union { u32 u[4]; bf16x8 v; } pw;
      pw.u[0] = cvtpk(exp2a(Sa[2 * ks][0]), exp2a(Sa[2 * ks][1])) & mw.x;
      pw.u[1] = cvtpk(exp2a(Sa[2 * ks][2]), exp2a(Sa[2 * ks][3])) & mw.y;
      pw.u[2] = cvtpk(exp2a(Sa[2 * ks + 1][0]), exp2a(Sa[2 * ks + 1][1])) & mw.z;
      pw.u[3] = cvtpk(exp2a(Sa[2 * ks + 1][2]), exp2a(Sa[2 * ks + 1][3])) & mw.w;
      Pa[ks] = pw.v;
    }

    // l accumulates over all tiles; O^T += V^T_frag * P_frag
    __builtin_amdgcn_s_setprio(1);
    lacc = __builtin_amdgcn_mfma_f32_16x16x32_bf16(ones.v, Pa[0], lacc, 0, 0, 0);
    lacc = __builtin_amdgcn_mfma_f32_16x16x32_bf16(ones.v, Pa[1], lacc, 0, 0, 0);
#pragma unroll
    for (int ks = 0; ks < 2; ks++) {
      bf16x8 vf[4];
#pragma unroll
      for (int di = 0; di < 4; di++)
        vf[di] = *(const bf16x8*)&VB[(di * 16 + c) * 64 + (((4 * ks + g) ^ swz) * 8)];
#pragma unroll
      for (int di = 0; di < 4; di++)
        Oa[di] = __builtin_amdgcn_mfma_f32_16x16x32_bf16(vf[di], Pa[ks], Oa[di], 0, 0, 0);
    }
    __builtin_amdgcn_s_setprio(0);

    // barrier without vmcnt drain (LDS ordering only)
    asm volatile("s_waitcnt lgkmcnt(0)\n\ts_barrier" ::: "memory");
  }

  // epilogue
  float inv = 1.f / lacc[0];
  int q = q0 + wv * 16 + c;
  size_t base = ((size_t)(b * S_ + q)) * DM + (size_t)h * HD;
#pragma unroll
  for (int di = 0; di < 4; di++) {
    uint2 o;
    o.x = cvtpk(Oa[di][0] * inv, Oa[di][1] * inv);
    o.y = cvtpk(Oa[di][2] * inv, Oa[di][3] * inv);
    *(uint2*)(ob + base + di * 16 + g * 4) = o;
  }
}

extern "C" void kernel_launch(void* const* d_in, const int* in_sizes, int n_in,
                              void* d_out, int out_size, void* d_ws, size_t ws_size,
                              hipStream_t stream) {
  const float* q  = (const float*)d_in[0];
  const int* kvm  = (const int*)d_in[1];
  const float* Wq = (const float*)d_in[2];
  const float* Wk = (const float*)d_in[3];
  const float* Wv = (const float*)d_in[4];
  const float* Wo = (const float*)d_in[5];
  const float* bo = (const float*)d_in[6];
  float* out = (float*)d_out;
  char* ws = (char*)d_ws;

  u16* Xbf   = (u16*)(ws);                       // 8 MB; reused as obuf post-gemm0
  u16* Wcat  = (u16*)(ws + (8u << 20));          // 6 MB (Wq|Wk|Wv)
  u16* Wobf  = (u16*)(ws + (14u << 20));         // 2 MB
  u16* qbuf  = (u16*)(ws + (16u << 20));         // 8 MB (B,H,S,64), pre-scaled
  u16* kbuf  = (u16*)(ws + (24u << 20));         // 8 MB compacted
  u16* vtbuf = (u16*)(ws + (32u << 20));         // 8 MB (B,H,64,S) sigma, compacted
  u16* mwg   = (u16*)(ws + (40u << 20));         // 8 KB compacted mask words
  int* posb  = (int*)(ws + (41u << 20));         // 16 KB prefix positions
  int* nvb   = (int*)(ws + (42u << 20));         // 8 B totals
  u16* obuf  = Xbf;

  mask_scan<<<B_, 256, 0, stream>>>(kvm, posb, nvb, mwg);
  cvt_all<<<2048, 256, 0, stream>>>(q, Wq, Wk, Wv, Wo, nvb, Xbf, Wcat, Wobf, vtbuf);
  gemm_bt<<<dim3(32, 24), 256, 0, stream>>>(Xbf, Wcat, qbuf, kbuf, vtbuf,
                                            kvm, posb);
  attn_kernel<<<512, 512, 0, stream>>>(qbuf, kbuf, vtbuf, mwg, nvb, obuf);
  gemm_n64<<<512, 256, 0, stream>>>(obuf, Wobf, bo, out);
}

// Round 16
// 109.315 us; speedup vs baseline: 1.0775x; 1.0002x over previous
//
#include <hip/hip_runtime.h>
#include <math.h>

#define B_ 2
#define S_ 2048
#define DM 1024
#define NH 16
#define HD 64

typedef unsigned short u16;
typedef unsigned int u32;
typedef __attribute__((ext_vector_type(8))) short bf16x8;
typedef __attribute__((ext_vector_type(4))) float f32x4;

// (1/sqrt(model_dim)) * log2(e): folded into Q at GEMM0 epilogue
#define C2SCALE 0.0450842200277800f

__device__ __forceinline__ u16 f2bf(float x) {
  unsigned u = __float_as_uint(x);
  u = (u + 0x7FFFu + ((u >> 16) & 1u)) >> 16;
  return (u16)u;
}

__device__ __forceinline__ u32 cvtpk(float lo, float hi) {
  u32 r;
  asm("v_cvt_pk_bf16_f32 %0, %1, %2" : "=v"(r) : "v"(lo), "v"(hi));
  return r;
}

__device__ __forceinline__ float exp2a(float x) {
  float r;
  asm("v_exp_f32 %0, %1" : "=v"(r) : "v"(x));
  return r;
}

__device__ __forceinline__ void gload_lds16(const u16* g, u16* l) {
  __builtin_amdgcn_global_load_lds((const __attribute__((address_space(1))) void*)g,
                                   (__attribute__((address_space(3))) void*)l, 16, 0, 0);
}

// sigma position within a 64-chunk (same permutation as the V^T producer)
__device__ __forceinline__ int sigpos(int w6) {
  return ((w6 >> 5) << 5) | (((w6 >> 2) & 3) << 3) | (((w6 >> 4) & 1) << 2) | (w6 & 3);
}

// per-batch exclusive prefix scan of kv_mask -> compacted positions posb,
// totals nvb, and sigma-ordered COMPACTED mask words (0xFFFF below total).
__global__ void mask_scan(const int* __restrict__ kvm, int* __restrict__ posb,
                          int* __restrict__ nvb, u16* __restrict__ mwg) {
  const int b = blockIdx.x;
  const int tid = threadIdx.x;  // 256
  const int lane = tid & 63, wv = tid >> 6;
  __shared__ int wsum[4];
  int v[8], s = 0;
  const int base = b * S_ + tid * 8;
#pragma unroll
  for (int j = 0; j < 8; j++) { v[j] = kvm[base + j] ? 1 : 0; s += v[j]; }
  int sc = s;
#pragma unroll
  for (int off = 1; off < 64; off <<= 1) {
    int t = __shfl_up(sc, off, 64);
    if (lane >= off) sc += t;
  }
  if (lane == 63) wsum[wv] = sc;
  __syncthreads();
  int woff = 0;
#pragma unroll
  for (int w = 0; w < 4; w++) woff += (w < wv) ? wsum[w] : 0;
  int run = woff + sc - s;  // exclusive prefix for this thread's chunk
#pragma unroll
  for (int j = 0; j < 8; j++) { posb[base + j] = run; run += v[j]; }
  const int total = wsum[0] + wsum[1] + wsum[2] + wsum[3];
  if (tid == 0) nvb[b] = total;
  for (int i = tid; i < S_; i += 256)
    mwg[b * S_ + (i & ~63) + sigpos(i & 63)] = (i < total) ? 0xFFFFu : 0u;
}

// fused f32->bf16 converts + V^T pad-column zeroing (PV inf/NaN safety)
__global__ void cvt_all(const float* __restrict__ q, const float* __restrict__ Wq,
                        const float* __restrict__ Wk, const float* __restrict__ Wv,
                        const float* __restrict__ Wo, const int* __restrict__ nvb,
                        u16* __restrict__ Xbf, u16* __restrict__ Wcat,
                        u16* __restrict__ Wobf, u16* __restrict__ vtbuf) {
  const int NQ4 = (B_ * S_ * DM) / 4;
  const int NW4 = (DM * DM) / 4;
  const int total = NQ4 + 4 * NW4;
  int i = blockIdx.x * blockDim.x + threadIdx.x;
  int stride = gridDim.x * blockDim.x;
  // zero V^T pad columns [nv, ceil64(nv)) for every (bh, d)
  for (int idx = i; idx < B_ * NH * HD * 64; idx += stride) {
    int col = idx & 63;
    int dd = (idx >> 6) & 63;
    int bh = idx >> 12;
    int nv = nvb[bh >> 4];
    int padw = ((nv + 63) & ~63) - nv;
    if (col < padw)
      vtbuf[((size_t)bh * HD + dd) * S_ + nv + col] = 0;
  }
  for (; i < total; i += stride) {
    const float* src;
    u16* dst;
    if (i < NQ4) {
      src = q + (size_t)i * 4; dst = Xbf + (size_t)i * 4;
    } else {
      int t = i - NQ4;
      if (t < NW4)            { src = Wq + (size_t)t * 4; dst = Wcat + (size_t)t * 4; }
      else if (t < 2 * NW4)   { src = Wk + (size_t)(t - NW4) * 4;     dst = Wcat + DM * DM + (size_t)(t - NW4) * 4; }
      else if (t < 3 * NW4)   { src = Wv + (size_t)(t - 2 * NW4) * 4; dst = Wcat + 2 * DM * DM + (size_t)(t - 2 * NW4) * 4; }
      else                    { src = Wo + (size_t)(t - 3 * NW4) * 4; dst = Wobf + (size_t)(t - 3 * NW4) * 4; }
    }
    float4 v = *(const float4*)src;
    ushort4 o;
    o.x = f2bf(v.x); o.y = f2bf(v.y); o.z = f2bf(v.z); o.w = f2bf(v.w);
    *(ushort4*)dst = o;
  }
}

// GEMM0: C[4096,3072] = X @ Wcat^T. 128x128 tile, BK=32, 768 blocks (3/CU),
// XCD-swizzled. 512 threads = 8 waves (4M x 2N), each wave 32x64 (acc 2x4)
// -> 24 waves/CU (2x the 4-wave version at identical per-CU LDS/MFMA traffic).
// Reg-staged double-buffered LDS with fused-pair XOR-swizzle layout
// ((m,k) -> row'=m>>1, col=(m&1)*32+k, slot = chunk ^ (row'&7));
// in-loop barrier is lgkmcnt-only (prefetches stay in flight).
// Q pre-scaled by C2SCALE; K/V scattered to COMPACTED kv positions (posb);
// V transposed + sigma-permuted. Invalid rows dropped.
__global__ __launch_bounds__(512, 6) void gemm_bt(
    const u16* __restrict__ A, const u16* __restrict__ Bw,
    u16* __restrict__ qo, u16* __restrict__ ko, u16* __restrict__ vo,
    const int* __restrict__ kvm, const int* __restrict__ posb) {
  __shared__ __align__(16) u16 As[2][64 * 64];
  __shared__ __align__(16) u16 Bs[2][64 * 64];
  const int K = DM;
  const int tid = threadIdx.x;
  const int wv = tid >> 6, lane = tid & 63;
  const int g = lane >> 4, c = lane & 15;
  const int wr = wv >> 1, wc = wv & 1;   // wr 0..3 (32-row band), wc 0..1 (64-col half)
  const int L = blockIdx.y * gridDim.x + blockIdx.x;
  const int cpx = (gridDim.x * gridDim.y) >> 3;
  const int Ls = (L & 7) * cpx + (L >> 3);
  const int Mb = (Ls & 31) << 7, Nb = (Ls >> 5) << 7;

  f32x4 acc[2][4];
#pragma unroll
  for (int i = 0; i < 2; i++)
#pragma unroll
    for (int j = 0; j < 4; j++) acc[i][j] = f32x4{0.f, 0.f, 0.f, 0.f};

  // staging: 512 chunks of 16B per matrix; thread owns exactly one per matrix.
  // chunk id: row' = tid>>3 (0..63), scol8 = tid&7;
  // logical m = row'*2 + (scol8>>2), k-chunk = scol8&3.
  const int srow = tid >> 3;
  const int scol8 = tid & 7;
  const int m1 = srow * 2 + (scol8 >> 2);
  const int kkc = (scol8 & 3) * 8;
  const u16* ag = A + (size_t)(Mb + m1) * K + kkc;       // + t*32
  const u16* bg = Bw + (size_t)(Nb + m1) * K + kkc;
  const int slot = scol8 ^ (srow & 7);
  u16* al = &As[0][srow * 64 + slot * 8];
  u16* bl = &Bs[0][srow * 64 + slot * 8];

  // prologue: tile0 -> regs -> buf0; tile1 -> regs
  bf16x8 ar = *(const bf16x8*)ag;
  bf16x8 br = *(const bf16x8*)bg;
  *(bf16x8*)al = ar;
  *(bf16x8*)bl = br;
  ar = *(const bf16x8*)(ag + 32);
  br = *(const bf16x8*)(bg + 32);
  __syncthreads();

  // lane-constant fragment read offsets (swizzle inverts to logical k = g*8)
  const int off = ((((c & 1) << 2) | g) ^ (c >> 1)) << 3;
  const int arb = (wr * 16 + (c >> 1)) * 64 + off;   // + mi*512
  const int brb = (wc * 32 + (c >> 1)) * 64 + off;   // + ni*512

  for (int t = 0; t < 32; ++t) {
    const int cur = t & 1;
    if (t + 1 < 32) {
      const int nb = (cur ^ 1) * 4096;
      *(bf16x8*)(al + nb) = ar;
      *(bf16x8*)(bl + nb) = br;
      if (t + 2 < 32) {
        ar = *(const bf16x8*)(ag + (t + 2) * 32);
        br = *(const bf16x8*)(bg + (t + 2) * 32);
      }
    }
    const u16* AB = &As[cur][0];
    const u16* BB = &Bs[cur][0];
    bf16x8 af[2], bfr[4];
#pragma unroll
    for (int mi = 0; mi < 2; mi++)
      af[mi] = *(const bf16x8*)&AB[arb + mi * 512];
#pragma unroll
    for (int ni = 0; ni < 4; ni++)
      bfr[ni] = *(const bf16x8*)&BB[brb + ni * 512];
#pragma unroll
    for (int mi = 0; mi < 2; mi++)
#pragma unroll
      for (int ni = 0; ni < 4; ni++)
        acc[mi][ni] = __builtin_amdgcn_mfma_f32_16x16x32_bf16(af[mi], bfr[ni], acc[mi][ni], 0, 0, 0);
    asm volatile("s_waitcnt lgkmcnt(0)\n\ts_barrier" ::: "memory");
  }

  const int nbase = Nb + wc * 64 + c;
  const int which = nbase >> 10;  // block-uniform (Nb is 128-aligned)
  if (which == 0) {
#pragma unroll
    for (int mi = 0; mi < 2; mi++) {
#pragma unroll
      for (int ni = 0; ni < 4; ni++) {
        int nn = nbase + ni * 16;
        int h = nn >> 6, d = nn & 63;
#pragma unroll
        for (int r = 0; r < 4; r++) {
          int row = Mb + wr * 32 + mi * 16 + g * 4 + r;
          int b0 = row >> 11, s0 = row & 2047;
          qo[(((size_t)(b0 * NH + h)) * S_ + s0) * HD + d] =
              f2bf(acc[mi][ni][r] * C2SCALE);
        }
      }
    }
  } else if (which == 1) {
#pragma unroll
    for (int mi = 0; mi < 2; mi++) {
#pragma unroll
      for (int r = 0; r < 4; r++) {
        int row = Mb + wr * 32 + mi * 16 + g * 4 + r;
        int b0 = row >> 11, s0 = row & 2047;
        if (kvm[b0 * S_ + s0]) {
          int p = posb[b0 * S_ + s0];
#pragma unroll
          for (int ni = 0; ni < 4; ni++) {
            int nn = (nbase + ni * 16) & 1023;
            ko[((size_t)(b0 * NH + (nn >> 6)) * S_ + p) * HD + (nn & 63)] =
                f2bf(acc[mi][ni][r]);
          }
        }
      }
    }
  } else {
#pragma unroll
    for (int mi = 0; mi < 2; mi++) {
#pragma unroll
      for (int r = 0; r < 4; r++) {
        int row = Mb + wr * 32 + mi * 16 + g * 4 + r;
        int b0 = row >> 11, s0 = row & 2047;
        if (kvm[b0 * S_ + s0]) {
          int p = posb[b0 * S_ + s0];
          int dst = (p & ~63) + sigpos(p & 63);
#pragma unroll
          for (int ni = 0; ni < 4; ni++) {
            int nn = (nbase + ni * 16) & 1023;
            vo[((size_t)((b0 * NH + (nn >> 6)) * HD + (nn & 63))) * S_ + dst] =
                f2bf(acc[mi][ni][r]);
          }
        }
      }
    }
  }
}

// GEMM1: out[4096,1024] = A @ Wo^T + bo. 128x64 tile -> 512 blocks (4/CU).
__global__ __launch_bounds__(256, 4) void gemm_n64(
    const u16* __restrict__ A, const u16* __restrict__ Bw,
    const float* __restrict__ bias, float* __restrict__ fo) {
  __shared__ __align__(16) u16 As[128 * 32];
  __shared__ __align__(16) u16 Bs[64 * 32];
  const int K = DM, N = DM;
  const int tid = threadIdx.x;
  const int wv = tid >> 6, lane = tid & 63;
  const int g = lane >> 4, c = lane & 15;
  const int wr = wv >> 1, wc = wv & 1;
  const int L = blockIdx.x;
  const int Ls = (L & 7) * 64 + (L >> 3);
  const int Mb = (Ls & 31) << 7, Nb = (Ls >> 5) << 6;

  f32x4 acc[4][2];
#pragma unroll
  for (int i = 0; i < 4; i++)
#pragma unroll
    for (int j = 0; j < 2; j++) acc[i][j] = f32x4{0.f, 0.f, 0.f, 0.f};

  for (int kb = 0; kb < K; kb += 32) {
#pragma unroll
    for (int it = 0; it < 2; ++it) {
      int id = it * 256 + tid;
      int m = id >> 2, kk = (id & 3) * 8;
      gload_lds16(A + (size_t)(Mb + m) * K + kb + kk, As + (it * 4 + wv) * 512);
    }
    {
      int m = tid >> 2, kk = (tid & 3) * 8;
      gload_lds16(Bw + (size_t)(Nb + m) * K + kb + kk, Bs + wv * 512);
    }
    __syncthreads();
    bf16x8 af[4], bfr[2];
#pragma unroll
    for (int mi = 0; mi < 4; mi++)
      af[mi] = *(const bf16x8*)(As + (wr * 64 + mi * 16 + c) * 32 + g * 8);
#pragma unroll
    for (int ni = 0; ni < 2; ni++)
      bfr[ni] = *(const bf16x8*)(Bs + (wc * 32 + ni * 16 + c) * 32 + g * 8);
#pragma unroll
    for (int mi = 0; mi < 4; mi++)
#pragma unroll
      for (int ni = 0; ni < 2; ni++)
        acc[mi][ni] = __builtin_amdgcn_mfma_f32_16x16x32_bf16(af[mi], bfr[ni], acc[mi][ni], 0, 0, 0);
    __syncthreads();
  }

#pragma unroll
  for (int mi = 0; mi < 4; mi++) {
#pragma unroll
    for (int ni = 0; ni < 2; ni++) {
      int n = Nb + wc * 32 + ni * 16 + c;
      float bv = bias[n];
#pragma unroll
      for (int r = 0; r < 4; r++) {
        int row = Mb + wr * 64 + mi * 16 + g * 4 + r;
        fo[(size_t)row * N + n] = acc[mi][ni][r] + bv;
      }
    }
  }
}

// Flash attention over COMPACTED kv (length nvb[b], tiles NT=ceil/64).
// Swapped-operand, fixed-shift softmax, KVBLK=64, 8 waves x 16 q.
// Reg-staged double-buffered K/V LDS, XOR-swizzled (conflict-free b128).
// p = v_exp(s); tail masking via AND on packed P; l via persistent MFMA acc.
__global__ __launch_bounds__(512, 4) void attn_kernel(
    const u16* __restrict__ qb, const u16* __restrict__ kb,
    const u16* __restrict__ vtb, const u16* __restrict__ mwg,
    const int* __restrict__ nvb, u16* __restrict__ ob) {
  __shared__ __align__(16) u16 Kl[2][64 * 64];
  __shared__ __align__(16) u16 Vl[2][64 * 64];
  __shared__ __align__(16) u16 MW[S_];

  const int tid = threadIdx.x;
  const int wv = tid >> 6, lane = tid & 63;
  const int g = lane >> 4, c = lane & 15;

  // XCD-aware bijective remap: XCD x owns bh range [4x,4x+4).
  const int L = blockIdx.x;
  const int j = L >> 3;
  const int bh = ((L & 7) << 2) | (j >> 4);
  const int qi = j & 15;
  const int b = bh >> 4, h = bh & 15;
  const int q0 = qi * 128;
  const size_t bhbase = (size_t)bh * (S_ * HD);
  const int NT = (nvb[b] + 63) >> 6;

  // compacted sigma-ordered mask words for this batch
  ((uint2*)MW)[tid] = ((const uint2*)(mwg + b * S_))[tid];

  bf16x8 qf[2];
#pragma unroll
  for (int ks = 0; ks < 2; ks++)
    qf[ks] = *(const bf16x8*)(qb + bhbase + (size_t)(q0 + wv * 16 + c) * HD + ks * 32 + g * 8);

  f32x4 Oa[4];
#pragma unroll
  for (int di = 0; di < 4; di++) Oa[di] = f32x4{0.f, 0.f, 0.f, 0.f};
  f32x4 lacc = f32x4{0.f, 0.f, 0.f, 0.f};

  union { u32 u[4]; bf16x8 v; } ones;
#pragma unroll
  for (int w = 0; w < 4; w++) ones.u[w] = 0x3F803F80u;

  const int srow = tid >> 3;
  const int scol8 = tid & 7;
  const u16* kg = kb + bhbase + (size_t)srow * HD + scol8 * 8;    // +t*4096
  const u16* vg = vtb + bhbase + (size_t)srow * S_ + scol8 * 8;   // +t*64
  const int wslot = scol8 ^ (srow & 7);
  u16* kld = &Kl[0][srow * 64 + wslot * 8];
  u16* vld = &Vl[0][srow * 64 + wslot * 8];

  // prologue: tile 0 -> regs -> buf0; tile 1 -> regs (NT >= 1 always)
  bf16x8 krg = *(const bf16x8*)kg;
  bf16x8 vrg = *(const bf16x8*)vg;
  *(bf16x8*)kld = krg;
  *(bf16x8*)vld = vrg;
  krg = *(const bf16x8*)(kg + 64 * HD);
  vrg = *(const bf16x8*)(vg + 64);
  __syncthreads();

  const int swz = c & 7;

  for (int t = 0; t < NT; ++t) {
    const int cur = t & 1;
    if (t + 1 < NT) {
      *(bf16x8*)(kld + (cur ^ 1) * 4096) = krg;
      *(bf16x8*)(vld + (cur ^ 1) * 4096) = vrg;
      if (t + 2 < NT) {
        krg = *(const bf16x8*)(kg + (t + 2) * (64 * HD));
        vrg = *(const bf16x8*)(vg + (t + 2) * 64);
      }
    }
    const u16* KB = &Kl[cur][0];
    const u16* VB = &Vl[cur][0];

    // S^T: Sa[ni], row = kv (ni*16 + 4g + r), col = q (c)
    f32x4 Sa[4];
#pragma unroll
    for (int ni = 0; ni < 4; ni++) Sa[ni] = f32x4{0.f, 0.f, 0.f, 0.f};
    __builtin_amdgcn_s_setprio(1);
#pragma unroll
    for (int ks = 0; ks < 2; ks++) {
      bf16x8 kf[4];
#pragma unroll
      for (int ni = 0; ni < 4; ni++)
        kf[ni] = *(const bf16x8*)&KB[(ni * 16 + c) * 64 + (((4 * ks + g) ^ swz) * 8)];
#pragma unroll
      for (int ni = 0; ni < 4; ni++)
        Sa[ni] = __builtin_amdgcn_mfma_f32_16x16x32_bf16(kf[ni], qf[ks], Sa[ni], 0, 0, 0);
    }
    __builtin_amdgcn_s_setprio(0);

    // p = 2^s (fixed-shift softmax); tail mask via bitwise AND
    bf16x8 Pa[2];
#pragma unroll
    for (int ks = 0; ks < 2; ks++) {
      uint4 mw = *(const uint4*)&MW[t * 64 + ks * 32 + g * 8];
      union { u32 u[4]; bf16x8 v; } pw;
      pw.u[0] = cvtpk(exp2a(Sa[2 * ks][0]), exp2a(Sa[2 * ks][1])) & mw.x;
      pw.u[1] = cvtpk(exp2a(Sa[2 * ks][2]), exp2a(Sa[2 * ks][3])) & mw.y;
      pw.u[2] = cvtpk(exp2a(Sa[2 * ks + 1][0]), exp2a(Sa[2 * ks + 1][1])) & mw.z;
      pw.u[3] = cvtpk(exp2a(Sa[2 * ks + 1][2]), exp2a(Sa[2 * ks + 1][3])) & mw.w;
      Pa[ks] = pw.v;
    }

    // l accumulates over all tiles; O^T += V^T_frag * P_frag
    __builtin_amdgcn_s_setprio(1);
    lacc = __builtin_amdgcn_mfma_f32_16x16x32_bf16(ones.v, Pa[0], lacc, 0, 0, 0);
    lacc = __builtin_amdgcn_mfma_f32_16x16x32_bf16(ones.v, Pa[1], lacc, 0, 0, 0);
#pragma unroll
    for (int ks = 0; ks < 2; ks++) {
      bf16x8 vf[4];
#pragma unroll
      for (int di = 0; di < 4; di++)
        vf[di] = *(const bf16x8*)&VB[(di * 16 + c) * 64 + (((4 * ks + g) ^ swz) * 8)];
#pragma unroll
      for (int di = 0; di < 4; di++)
        Oa[di] = __builtin_amdgcn_mfma_f32_16x16x32_bf16(vf[di], Pa[ks], Oa[di], 0, 0, 0);
    }
    __builtin_amdgcn_s_setprio(0);

    // barrier without vmcnt drain (LDS ordering only)
    asm volatile("s_waitcnt lgkmcnt(0)\n\ts_barrier" ::: "memory");
  }

  // epilogue
  float inv = 1.f / lacc[0];
  int q = q0 + wv * 16 + c;
  size_t base = ((size_t)(b * S_ + q)) * DM + (size_t)h * HD;
#pragma unroll
  for (int di = 0; di < 4; di++) {
    uint2 o;
    o.x = cvtpk(Oa[di][0] * inv, Oa[di][1] * inv);
    o.y = cvtpk(Oa[di][2] * inv, Oa[di][3] * inv);
    *(uint2*)(ob + base + di * 16 + g * 4) = o;
  }
}

extern "C" void kernel_launch(void* const* d_in, const int* in_sizes, int n_in,
                              void* d_out, int out_size, void* d_ws, size_t ws_size,
                              hipStream_t stream) {
  const float* q  = (const float*)d_in[0];
  const int* kvm  = (const int*)d_in[1];
  const float* Wq = (const float*)d_in[2];
  const float* Wk = (const float*)d_in[3];
  const float* Wv = (const float*)d_in[4];
  const float* Wo = (const float*)d_in[5];
  const float* bo = (const float*)d_in[6];
  float* out = (float*)d_out;
  char* ws = (char*)d_ws;

  u16* Xbf   = (u16*)(ws);                       // 8 MB; reused as obuf post-gemm0
  u16* Wcat  = (u16*)(ws + (8u << 20));          // 6 MB (Wq|Wk|Wv)
  u16* Wobf  = (u16*)(ws + (14u << 20));         // 2 MB
  u16* qbuf  = (u16*)(ws + (16u << 20));         // 8 MB (B,H,S,64), pre-scaled
  u16* kbuf  = (u16*)(ws + (24u << 20));         // 8 MB compacted
  u16* vtbuf = (u16*)(ws + (32u << 20));         // 8 MB (B,H,64,S) sigma, compacted
  u16* mwg   = (u16*)(ws + (40u << 20));         // 8 KB compacted mask words
  int* posb  = (int*)(ws + (41u << 20));         // 16 KB prefix positions
  int* nvb   = (int*)(ws + (42u << 20));         // 8 B totals
  u16* obuf  = Xbf;

  mask_scan<<<B_, 256, 0, stream>>>(kvm, posb, nvb, mwg);
  cvt_all<<<2048, 256, 0, stream>>>(q, Wq, Wk, Wv, Wo, nvb, Xbf, Wcat, Wobf, vtbuf);
  gemm_bt<<<dim3(32, 24), 512, 0, stream>>>(Xbf, Wcat, qbuf, kbuf, vtbuf,
                                            kvm, posb);
  attn_kernel<<<512, 512, 0, stream>>>(qbuf, kbuf, vtbuf, mwg, nvb, obuf);
  gemm_n64<<<512, 256, 0, stream>>>(obuf, Wobf, bo, out);
}